// Round 3
// baseline (324.576 us; speedup 1.0000x reference)
//
#include <hip/hip_runtime.h>
#include <math.h>

// Pool2d: 3x3 max pool, stride 2, pad 1 (fill 0.0), dilation 1.
// X: (32,192,224,224) f32 NCHW -> Y: (32,192,112,112) f32.
// Floor: 1.233 GB read + 0.308 GB write => ~237-245 us @ 6.3-6.5 TB/s.
//
// R3: one wave per channel, streaming rows. Every input row loaded EXACTLY
// once (compulsory fetch, no cache reliance): lanes 0..55 each load one
// aligned float4 -> one wave instruction reads the whole 896-B row
// contiguously. Rolling register buffer of per-row horizontal 3-tap maxes;
// rows processed in (even, odd) pairs, emitting output row r/2 =
// max(h(r-1), h(r), h(r+1)). x-1 tap via __shfl_up; left pad = 0.0.

namespace {
constexpr int H = 224;
constexpr int W = 224;
constexpr int HO = 112;
constexpr int WO = 112;
constexpr int NC = 32 * 192;           // 6144 channels = 6144 waves
}

__global__ __launch_bounds__(256) void pool3x3s2_stream(
    const float* __restrict__ X, float* __restrict__ Y) {
  const int gtid = blockIdx.x * blockDim.x + threadIdx.x;
  const int ch   = gtid >> 6;          // one wave64 per channel
  const int lane = threadIdx.x & 63;
  if (ch >= NC) return;

  const float* __restrict__ img = X + (size_t)ch * (H * W);
  float* __restrict__ out = Y + (size_t)ch * (HO * WO);

  const bool active = lane < 56;       // 56 lanes x 4 floats = 224 = W
  const float* __restrict__ p = img + 4 * lane;

  // h(-1): the padded row contributes fill value 0.0 everywhere.
  float2 hprev = make_float2(0.0f, 0.0f);

#pragma unroll 4
  for (int r = 0; r < H; r += 2) {
    // Load rows r and r+1; each wave instruction = 896 B contiguous.
    float4 v = active ? *reinterpret_cast<const float4*>(p)
                      : make_float4(0.f, 0.f, 0.f, 0.f);
    float4 w = active ? *reinterpret_cast<const float4*>(p + W)
                      : make_float4(0.f, 0.f, 0.f, 0.f);
    p += 2 * W;

    // x-1 tap from the previous lane's last element; lane 0 gets pad 0.0.
    float vm1 = __shfl_up(v.w, 1);
    float wm1 = __shfl_up(w.w, 1);
    if (lane == 0) { vm1 = 0.0f; wm1 = 0.0f; }

    // Horizontal 3-tap maxes: lane covers output cols 2*lane, 2*lane+1
    // (taps x = 4l-1..4l+1 and 4l+1..4l+3).
    float2 hv, hw;
    hv.x = fmaxf(fmaxf(vm1, v.x), v.y);
    hv.y = fmaxf(fmaxf(v.y, v.z), v.w);
    hw.x = fmaxf(fmaxf(wm1, w.x), w.y);
    hw.y = fmaxf(fmaxf(w.y, w.z), w.w);

    // Output row oy = r/2 taps input rows r-1 (hprev), r (hv), r+1 (hw).
    float2 o;
    o.x = fmaxf(fmaxf(hprev.x, hv.x), hw.x);
    o.y = fmaxf(fmaxf(hprev.y, hv.y), hw.y);
    if (active)
      *reinterpret_cast<float2*>(out + (r >> 1) * WO + 2 * lane) = o;

    hprev = hw;                        // h(r+1) feeds output row r/2 + 1
  }
}

extern "C" void kernel_launch(void* const* d_in, const int* in_sizes, int n_in,
                              void* d_out, int out_size, void* d_ws, size_t ws_size,
                              hipStream_t stream) {
  const float* X = (const float*)d_in[0];
  float* Y = (float*)d_out;
  // 6144 waves, 4 waves/block -> 1536 blocks; 6 blocks/CU co-resident.
  pool3x3s2_stream<<<NC / 4, 256, 0, stream>>>(X, Y);
}

// Round 5
// 274.400 us; speedup vs baseline: 1.1829x; 1.1829x over previous
//
#include <hip/hip_runtime.h>
#include <math.h>

// Pool2d: 3x3 max pool, stride 2, pad 1 (fill 0.0), dilation 1.
// X: (32,192,224,224) f32 NCHW -> Y: (32,192,112,112) f32.
// Compulsory traffic: 1.233 GB read + 0.308 GB write.
//
// R5 (= R4 with compile fix): 2x4 output tile per thread.
//  - 5 input rows per 8 outputs (R1 touched 6: every odd row twice via L1).
//  - lane access pattern kept at R1's proven 16 B/lane, 32-B stride.
//  - exact-cover grid, no grid-stride loop: 10 x float4 + 5 scalar loads
//    issue back-to-back per thread -> max MLP, no loop-carried waitcnt.
//  - nontemporal stores (native ext_vector float4 -- HIP_vector_type is
//    rejected by the builtin): Y is never re-read; don't evict read lines.

namespace {
constexpr int H = 224;
constexpr int W = 224;
constexpr int HO = 112;
constexpr int WO = 112;
constexpr int QPR = WO / 4;              // 28 quads per output row
constexpr int PAIRS = HO / 2;            // 56 output-row pairs
constexpr int NC = 32 * 192;
constexpr int TOTAL = NC * PAIRS * QPR;  // 9,633,792 threads (= 37632 blocks)

typedef float v4f __attribute__((ext_vector_type(4)));
}

__global__ __launch_bounds__(256) void pool3x3s2_tile2x4(
    const float* __restrict__ X, float* __restrict__ Y) {
  const int idx = blockIdx.x * blockDim.x + threadIdx.x;  // exact cover
  const int q  = idx % QPR;              // outputs 4q..4q+3
  const int t  = idx / QPR;
  const int p  = t % PAIRS;              // output rows 2p, 2p+1
  const int nc = t / PAIRS;

  const float* __restrict__ img = X + (size_t)nc * (H * W);
  const int ixs = 8 * q;                 // window x = [ixs-1, ixs+7]
  const int iy0 = 4 * p - 1;             // rows iy0..iy0+4; only iy=-1 OOB

  // Per-row horizontal 3-tap maxes for 4 output cols, 5 rows.
  float h[5][4];
#pragma unroll
  for (int r = 0; r < 5; ++r) {
    const int iy = iy0 + r;
    float a, b0, b1, b2, b3, b4, b5, b6, b7;
    if (iy >= 0) {                       // iy <= 223 always
      const float* __restrict__ row = img + iy * W + ixs;
      a = (ixs > 0) ? row[-1] : 0.0f;    // left pad = fill 0.0
      const v4f v0 = *reinterpret_cast<const v4f*>(row);
      const v4f v1 = *reinterpret_cast<const v4f*>(row + 4);
      b0 = v0.x; b1 = v0.y; b2 = v0.z; b3 = v0.w;
      b4 = v1.x; b5 = v1.y; b6 = v1.z; b7 = v1.w;
    } else {                             // padded row -> fill 0.0
      a = b0 = b1 = b2 = b3 = b4 = b5 = b6 = b7 = 0.0f;
    }
    h[r][0] = fmaxf(fmaxf(a,  b0), b1);  // col j taps x = 2j-1..2j+1
    h[r][1] = fmaxf(fmaxf(b1, b2), b3);
    h[r][2] = fmaxf(fmaxf(b3, b4), b5);
    h[r][3] = fmaxf(fmaxf(b5, b6), b7);
  }

  v4f o0, o1;
  o0.x = fmaxf(fmaxf(h[0][0], h[1][0]), h[2][0]);  // oy = 2p
  o0.y = fmaxf(fmaxf(h[0][1], h[1][1]), h[2][1]);
  o0.z = fmaxf(fmaxf(h[0][2], h[1][2]), h[2][2]);
  o0.w = fmaxf(fmaxf(h[0][3], h[1][3]), h[2][3]);
  o1.x = fmaxf(fmaxf(h[2][0], h[3][0]), h[4][0]);  // oy = 2p+1
  o1.y = fmaxf(fmaxf(h[2][1], h[3][1]), h[4][1]);
  o1.z = fmaxf(fmaxf(h[2][2], h[3][2]), h[4][2]);
  o1.w = fmaxf(fmaxf(h[2][3], h[3][3]), h[4][3]);

  float* __restrict__ out = Y + ((size_t)nc * HO + 2 * p) * WO + 4 * q;
  __builtin_nontemporal_store(o0, reinterpret_cast<v4f*>(out));
  __builtin_nontemporal_store(o1, reinterpret_cast<v4f*>(out + WO));
}

extern "C" void kernel_launch(void* const* d_in, const int* in_sizes, int n_in,
                              void* d_out, int out_size, void* d_ws, size_t ws_size,
                              hipStream_t stream) {
  const float* X = (const float*)d_in[0];
  float* Y = (float*)d_out;
  pool3x3s2_tile2x4<<<TOTAL / 256, 256, 0, stream>>>(X, Y);
}